// Round 9
// baseline (74.629 us; speedup 1.0000x reference)
//
#include <hip/hip_runtime.h>

#define R_    116
#define DIN_  116
#define H_    256

typedef float  f32x4   __attribute__((ext_vector_type(4)));
typedef float  f32x16  __attribute__((ext_vector_type(16)));
typedef short  short8  __attribute__((ext_vector_type(8)));
typedef int    int4v   __attribute__((ext_vector_type(4)));
typedef int    int2v   __attribute__((ext_vector_type(2)));

// ---- LDS layout (bytes). 16B-block XOR swizzle per row (block ^= row&7).
#define AT_OFF   0        // At [128 c][128 r] bf16 pitch 256B : bb=(r>>3)^(c&7)
#define X_OFF    32768    // X  [128 r][128 k] bf16 pitch 256B : bb=(k>>3)^(r&7)
#define XS_OFF   65536    // XS [128 f][128 r] bf16 pitch 256B : bb=(r>>3)^(f&7)
#define H1_OFF   98304    // H1 [116 c][256 f] bf16 pitch 512B : bb=(f>>3)^(c&7)
#define DINV_OFF 157696   // 128 f32 (persistent)
#define RED_OFF  158208   // 16 f32
#define LDS_SIZE 158272

#define Z16 {0.f,0.f,0.f,0.f,0.f,0.f,0.f,0.f,0.f,0.f,0.f,0.f,0.f,0.f,0.f,0.f}

__device__ __forceinline__ short f2bf(float f) {
  union { float f; unsigned u; } x; x.f = f;
  unsigned r = x.u + 0x7fffu + ((x.u >> 16) & 1u);
  return (short)(r >> 16);
}
__device__ __forceinline__ float bf2f(short s) {
  union { unsigned u; float f; } x;
  x.u = ((unsigned)(unsigned short)s) << 16;
  return x.f;
}
__device__ __forceinline__ unsigned pack2(float lo, float hi) {
  return (unsigned)(unsigned short)f2bf(lo) | ((unsigned)(unsigned short)f2bf(hi) << 16);
}

// Pre-transpose weights to bf16 Wt[f][k], zero-padded K (layer 1).
__global__ void __launch_bounds__(256) wt_setup(const float* __restrict__ W1,
                                                const float* __restrict__ W2,
                                                short* __restrict__ W1t,
                                                short* __restrict__ W2t) {
  int idx = blockIdx.x * 256 + threadIdx.x;      // 384 blocks
  if (idx < 32768) {                             // W1t [256][128]
    int f = idx >> 7, k = idx & 127;
    float v = (k < DIN_) ? W1[k * H_ + f] : 0.f;
    W1t[idx] = f2bf(v);
  } else {                                       // W2t [256][256]
    int j = idx - 32768;
    int f = j >> 8, k = j & 255;
    W2t[j] = f2bf(W2[k * H_ + f]);
  }
}

// 8 waves (512 thr), 32x32x16 MFMA. wave = (wm = row/col half, wf4 = 32-wide f tile).
// A/B frag: lane l holds [row l&31][k = (l>>5)*8 + j].
// C/D frag: col = l&31, row = (reg&3) + 8*(reg>>2) + 4*(l>>5).
__global__ void __launch_bounds__(512, 2) gnn_fused(
    const float* __restrict__ mM, const float* __restrict__ nf,
    const float* __restrict__ b1, const float* __restrict__ b2,
    const float* __restrict__ Wc, const float* __restrict__ bc,
    const short* __restrict__ W1t, const short* __restrict__ W2t,
    float* __restrict__ out)
{
  extern __shared__ char smem[];
  const int b    = blockIdx.x;
  const int tid  = threadIdx.x;
  const int lane = tid & 63;
  const int w    = tid >> 6;     // 0..7
  const int wm   = w >> 2;       // 0..1 : row/col half (0-63 vs 64-127)
  const int wf4  = w & 3;        // 0..3 : 32-wide f tile within 128-half
  const int n32  = lane & 31;
  const int hi   = lane >> 5;
  const int s7   = n32 & 7;

  // ---- zero At + X (64KB; covers all padding) ----
  for (int t = tid; t < 65536 / 16; t += 512)
    ((int4v*)smem)[t] = (int4v){0, 0, 0, 0};
  __syncthreads();

  // ---- fill At (transposed, relu, +1 diag) and X (bf16), coalesced f32x4 reads ----
  {
    const float* mB = mM + (size_t)b * (R_ * R_);
    const float* xB = nf + (size_t)b * (R_ * DIN_);
    for (int t4 = tid; t4 < (R_ * R_) / 4; t4 += 512) {
      f32x4 v4 = ((const f32x4*)mB)[t4];
      f32x4 x4 = ((const f32x4*)xB)[t4];
      int i0 = t4 * 4;
      int r = i0 / R_, c0 = i0 - r * R_;          // c0 % 4 == 0 (116 % 4 == 0)
#pragma unroll
      for (int e = 0; e < 4; ++e) {               // At: rows differ -> scalar stores
        int c = c0 + e;
        float v = v4[e];
        v = v > 0.f ? v : 0.f;
        if (r == c) v += 1.f;
        int ba = (r >> 3) ^ (c & 7);
        *(short*)(smem + AT_OFF + c * 256 + ba * 16 + (r & 7) * 2) = f2bf(v);
      }
      {                                           // X: same row -> one 8B store
        int bx = (c0 >> 3) ^ (r & 7);
        int2v px;
        px[0] = (int)pack2(x4[0], x4[1]);
        px[1] = (int)pack2(x4[2], x4[3]);
        *(int2v*)(smem + X_OFF + r * 256 + bx * 16 + (c0 & 7) * 2) = px;
      }
    }
  }
  __syncthreads();

  // ---- deg/dinv: 4 threads per row -> persistent DINV region ----
  {
    float* dinvp = (float*)(smem + DINV_OFF);
    int row = tid >> 2, part = tid & 3;
    float s = 0.f;
#pragma unroll
    for (int j = 0; j < 4; ++j) {
      int bb = (part * 4 + j) ^ (row & 7);
      short8 v = *(const short8*)(smem + AT_OFF + row * 256 + bb * 16);
#pragma unroll
      for (int e = 0; e < 8; ++e) s += bf2f(v[e]);
    }
    s += __shfl_xor(s, 1);
    s += __shfl_xor(s, 2);
    if (part == 0) dinvp[row] = (row < R_) ? rsqrtf(s) : 0.f;
  }
  __syncthreads();

  // dinv register-resident (persistent region -> no extra barrier):
  // dvq[mt][rq] = dinv[wm*64 + mt*32 + rq*8 + hi*4 .. +3]  (C/D row quads)
  // dvc2[ct]    = dinv[wm*64 + ct*32 + n32]                (C/D col map)
  const float* dinvp = (const float*)(smem + DINV_OFF);
  f32x4 dvq[2][4];
#pragma unroll
  for (int mt = 0; mt < 2; ++mt)
#pragma unroll
    for (int rq = 0; rq < 4; ++rq)
      dvq[mt][rq] = *(const f32x4*)(dinvp + wm * 64 + mt * 32 + rq * 8 + hi * 4);
  float dvc2[2];
  dvc2[0] = dinvp[wm * 64 + n32];
  dvc2[1] = dinvp[wm * 64 + 32 + n32];

  const int fhb = wf4 * 32 + n32;    // XS row (f within 128-half)
  float ps0 = 0.f, ps1 = 0.f;

  // ================= Layer 1 =================
#pragma unroll 1
  for (int hf = 0; hf < 2; ++hf) {
    const int fB = hf * 128 + wf4 * 32 + n32;   // per-lane f (B-frag col)
    // ---- phase A: xw = X @ W1 : 32 f x 64 r per wave, K=128 (8 steps of 16) ----
    f32x16 acc[2];
#pragma unroll
    for (int mt = 0; mt < 2; ++mt) acc[mt] = (f32x16)Z16;
#pragma unroll
    for (int ks = 0; ks < 8; ++ks) {
      short8 wf = *(const short8*)(W1t + (size_t)fB * 128 + ks * 16 + hi * 8);
#pragma unroll
      for (int mt = 0; mt < 2; ++mt) {
        int r = wm * 64 + mt * 32 + n32;
        int bb = (ks * 2 + hi) ^ s7;            // r&7 == s7
        short8 af = *(const short8*)(smem + X_OFF + r * 256 + bb * 16);
        acc[mt] = __builtin_amdgcn_mfma_f32_32x32x16_bf16(af, wf, acc[mt], 0, 0, 0);
      }
    }
    // scale by dinv[r] -> XS[f][r], 8B packed stores (4 consecutive r per reg-quad)
#pragma unroll
    for (int mt = 0; mt < 2; ++mt)
#pragma unroll
      for (int rq = 0; rq < 4; ++rq) {
        int r0 = wm * 64 + mt * 32 + rq * 8 + hi * 4;
        f32x4 dv = dvq[mt][rq];
        int2v pk;
        pk[0] = (int)pack2(acc[mt][rq * 4 + 0] * dv[0], acc[mt][rq * 4 + 1] * dv[1]);
        pk[1] = (int)pack2(acc[mt][rq * 4 + 2] * dv[2], acc[mt][rq * 4 + 3] * dv[3]);
        int bb = (r0 >> 3) ^ s7;                // fhb&7 == s7
        *(int2v*)(smem + XS_OFF + fhb * 256 + bb * 16 + hi * 8) = pk;
      }
    __syncthreads();

    // ---- phase B: agg[f][c] = xs @ At^T : 32 f x 64 c per wave, K=128 ----
    f32x16 acc2[2];
#pragma unroll
    for (int ct = 0; ct < 2; ++ct) acc2[ct] = (f32x16)Z16;
#pragma unroll
    for (int ks = 0; ks < 8; ++ks) {
      int bb = (ks * 2 + hi) ^ s7;
      short8 ax = *(const short8*)(smem + XS_OFF + fhb * 256 + bb * 16);
#pragma unroll
      for (int ct = 0; ct < 2; ++ct) {
        int c = wm * 64 + ct * 32 + n32;        // c&7 == s7
        short8 atf = *(const short8*)(smem + AT_OFF + c * 256 + bb * 16);
        acc2[ct] = __builtin_amdgcn_mfma_f32_32x32x16_bf16(ax, atf, acc2[ct], 0, 0, 0);
      }
    }
    // epilogue: h1 = leaky(dinv[c]*agg + b1[f]) -> H1[c][f] (rows c<116 only)
#pragma unroll
    for (int rq = 0; rq < 4; ++rq) {
      const int f0 = hf * 128 + wf4 * 32 + rq * 8 + hi * 4;
      f32x4 bv = *(const f32x4*)(b1 + f0);
#pragma unroll
      for (int ct = 0; ct < 2; ++ct) {
        int c = wm * 64 + ct * 32 + n32;
        if (c < R_) {
          float dv = dvc2[ct];
          float h0 = dv * acc2[ct][rq * 4 + 0] + bv[0]; h0 = h0 > 0.f ? h0 : 0.2f * h0;
          float h1 = dv * acc2[ct][rq * 4 + 1] + bv[1]; h1 = h1 > 0.f ? h1 : 0.2f * h1;
          float h2 = dv * acc2[ct][rq * 4 + 2] + bv[2]; h2 = h2 > 0.f ? h2 : 0.2f * h2;
          float h3 = dv * acc2[ct][rq * 4 + 3] + bv[3]; h3 = h3 > 0.f ? h3 : 0.2f * h3;
          int bbh = (f0 >> 3) ^ s7;             // c&7 == s7
          int2v pk;
          pk[0] = (int)pack2(h0, h1);
          pk[1] = (int)pack2(h2, h3);
          *(int2v*)(smem + H1_OFF + c * 512 + bbh * 16 + hi * 8) = pk;
        }
      }
    }
    __syncthreads();
  }

  // ================= Layer 2 =================
#pragma unroll 1
  for (int hf = 0; hf < 2; ++hf) {
    const int fB = hf * 128 + wf4 * 32 + n32;
    // ---- phase A: xw2 = H1 @ W2, K=256 (16 steps of 16); clamp rows >= 116 ----
    f32x16 acc[2];
#pragma unroll
    for (int mt = 0; mt < 2; ++mt) acc[mt] = (f32x16)Z16;
#pragma unroll
    for (int ks = 0; ks < 16; ++ks) {
      short8 wf = *(const short8*)(W2t + (size_t)fB * 256 + ks * 16 + hi * 8);
#pragma unroll
      for (int mt = 0; mt < 2; ++mt) {
        int r = wm * 64 + mt * 32 + n32;
        int rc = r < R_ ? r : 0;                // clamp: junk killed by dinv=0
        int bb = (ks * 2 + hi) ^ (rc & 7);
        short8 af = *(const short8*)(smem + H1_OFF + rc * 512 + bb * 16);
        acc[mt] = __builtin_amdgcn_mfma_f32_32x32x16_bf16(af, wf, acc[mt], 0, 0, 0);
      }
    }
#pragma unroll
    for (int mt = 0; mt < 2; ++mt)
#pragma unroll
      for (int rq = 0; rq < 4; ++rq) {
        int r0 = wm * 64 + mt * 32 + rq * 8 + hi * 4;
        f32x4 dv = dvq[mt][rq];
        int2v pk;
        pk[0] = (int)pack2(acc[mt][rq * 4 + 0] * dv[0], acc[mt][rq * 4 + 1] * dv[1]);
        pk[1] = (int)pack2(acc[mt][rq * 4 + 2] * dv[2], acc[mt][rq * 4 + 3] * dv[3]);
        int bb = (r0 >> 3) ^ s7;
        *(int2v*)(smem + XS_OFF + fhb * 256 + bb * 16 + hi * 8) = pk;
      }
    __syncthreads();

    // ---- phase B ----
    f32x16 acc2[2];
#pragma unroll
    for (int ct = 0; ct < 2; ++ct) acc2[ct] = (f32x16)Z16;
#pragma unroll
    for (int ks = 0; ks < 8; ++ks) {
      int bb = (ks * 2 + hi) ^ s7;
      short8 ax = *(const short8*)(smem + XS_OFF + fhb * 256 + bb * 16);
#pragma unroll
      for (int ct = 0; ct < 2; ++ct) {
        int c = wm * 64 + ct * 32 + n32;
        short8 atf = *(const short8*)(smem + AT_OFF + c * 256 + bb * 16);
        acc2[ct] = __builtin_amdgcn_mfma_f32_32x32x16_bf16(ax, atf, acc2[ct], 0, 0, 0);
      }
    }
    // epilogue: h2 -> classifier partial dot (vectorized Wc reads)
#pragma unroll
    for (int rq = 0; rq < 4; ++rq) {
      const int f0 = hf * 128 + wf4 * 32 + rq * 8 + hi * 4;
      f32x4 bv = *(const f32x4*)(b2 + f0);
#pragma unroll
      for (int ct = 0; ct < 2; ++ct) {
        int c = wm * 64 + ct * 32 + n32;
        if (c < R_) {
          float dv = dvc2[ct];
          float h0 = dv * acc2[ct][rq * 4 + 0] + bv[0]; h0 = h0 > 0.f ? h0 : 0.2f * h0;
          float h1 = dv * acc2[ct][rq * 4 + 1] + bv[1]; h1 = h1 > 0.f ? h1 : 0.2f * h1;
          float h2 = dv * acc2[ct][rq * 4 + 2] + bv[2]; h2 = h2 > 0.f ? h2 : 0.2f * h2;
          float h3 = dv * acc2[ct][rq * 4 + 3] + bv[3]; h3 = h3 > 0.f ? h3 : 0.2f * h3;
          f32x4 wc0 = *(const f32x4*)(Wc + (size_t)c * H_ + f0);
          f32x4 wc1 = *(const f32x4*)(Wc + (size_t)(H_ * R_) + (size_t)c * H_ + f0);
          ps0 += h0 * wc0[0] + h1 * wc0[1] + h2 * wc0[2] + h3 * wc0[3];
          ps1 += h0 * wc1[0] + h1 * wc1[1] + h2 * wc1[2] + h3 * wc1[3];
        }
      }
    }
    __syncthreads();
  }

  // ---- classifier reduction ----
#pragma unroll
  for (int off = 32; off; off >>= 1) {
    ps0 += __shfl_xor(ps0, off, 64);
    ps1 += __shfl_xor(ps1, off, 64);
  }
  float* red = (float*)(smem + RED_OFF);
  if (lane == 0) { red[w * 2] = ps0; red[w * 2 + 1] = ps1; }
  __syncthreads();
  if (tid == 0) {
    float s0 = 0.f, s1 = 0.f;
#pragma unroll
    for (int i = 0; i < 8; ++i) { s0 += red[i * 2]; s1 += red[i * 2 + 1]; }
    out[b * 2 + 0] = s0 + bc[0];
    out[b * 2 + 1] = s1 + bc[1];
  }
}

extern "C" void kernel_launch(void* const* d_in, const int* in_sizes, int n_in,
                              void* d_out, int out_size, void* d_ws, size_t ws_size,
                              hipStream_t stream) {
  const float* mM = (const float*)d_in[0];
  const float* nf = (const float*)d_in[1];
  const float* W1 = (const float*)d_in[2];
  const float* b1 = (const float*)d_in[3];
  const float* W2 = (const float*)d_in[4];
  const float* b2 = (const float*)d_in[5];
  const float* Wc = (const float*)d_in[6];
  const float* bc = (const float*)d_in[7];
  float* out = (float*)d_out;

  short* W1t = (short*)d_ws;            // 32768 bf16
  short* W2t = W1t + 32768;             // 65536 bf16

  wt_setup<<<384, 256, 0, stream>>>(W1, W2, W1t, W2t);

  hipFuncSetAttribute((const void*)gnn_fused,
                      hipFuncAttributeMaxDynamicSharedMemorySize, LDS_SIZE);
  gnn_fused<<<512, 512, LDS_SIZE, stream>>>(mM, nf, b1, b2, Wc, bc, W1t, W2t, out);
}